// Round 1
// baseline (183.996 us; speedup 1.0000x reference)
//
#include <hip/hip_runtime.h>

// MeanPool (global_mean_pool): x [N=1e6, F=256] f32, batch [N] sorted int,
// out [G=1024, F=256] f32 = segment_sum(x) / max(count, 1).
//
// Memory-bound streaming kernel: 1 block per graph, binary-search segment
// bounds in the sorted batch array, float4-vectorized coalesced row reads,
// 4 row-teams x 64 lanes, 4-deep unroll for MLP (4 loads in flight/thread).

__device__ __forceinline__ float4 f4add(float4 a, float4 b) {
    return make_float4(a.x + b.x, a.y + b.y, a.z + b.z, a.w + b.w);
}

__global__ __launch_bounds__(256) void meanpool_kernel(
    const float* __restrict__ x,
    const int* __restrict__ batch,
    float* __restrict__ out,
    int N)
{
    const int g = blockIdx.x;

    // --- segment bounds via binary search (batch is sorted ascending) ---
    __shared__ int s_b[2];
    if (threadIdx.x < 2) {
        const int target = g + (int)threadIdx.x;   // lower_bound(target)
        int lo = 0, hi = N;
        while (lo < hi) {
            int mid = (lo + hi) >> 1;
            if (batch[mid] < target) lo = mid + 1; else hi = mid;
        }
        s_b[threadIdx.x] = lo;
    }
    __syncthreads();
    const int start = s_b[0];
    const int end   = s_b[1];
    const int count = end - start;

    // --- streaming sum: 4 row-teams (r) x 64 lanes (q), float4 per lane ---
    const int q = threadIdx.x & 63;   // float4 column within the 256-f row
    const int r = threadIdx.x >> 6;   // row-team 0..3
    const float4* __restrict__ xv = reinterpret_cast<const float4*>(x);

    float4 a0 = make_float4(0.f, 0.f, 0.f, 0.f);
    float4 a1 = a0, a2 = a0, a3 = a0;

    int i = start + r;
    // main loop: 4 independent accumulators -> 4 outstanding dwordx4 loads
    for (; i + 12 < end; i += 16) {
        a0 = f4add(a0, xv[(size_t)(i     ) * 64 + q]);
        a1 = f4add(a1, xv[(size_t)(i +  4) * 64 + q]);
        a2 = f4add(a2, xv[(size_t)(i +  8) * 64 + q]);
        a3 = f4add(a3, xv[(size_t)(i + 12) * 64 + q]);
    }
    for (; i < end; i += 4) {
        a0 = f4add(a0, xv[(size_t)i * 64 + q]);
    }
    a0 = f4add(f4add(a0, a1), f4add(a2, a3));

    // --- cross-team reduction in LDS (3 partials), then scale + store ---
    __shared__ float4 s_part[3][64];
    if (r > 0) s_part[r - 1][q] = a0;
    __syncthreads();
    if (r == 0) {
        a0 = f4add(a0, s_part[0][q]);
        a0 = f4add(a0, s_part[1][q]);
        a0 = f4add(a0, s_part[2][q]);
        const float inv = 1.0f / (float)(count > 1 ? count : 1);
        float4* __restrict__ outv = reinterpret_cast<float4*>(out);
        outv[(size_t)g * 64 + q] =
            make_float4(a0.x * inv, a0.y * inv, a0.z * inv, a0.w * inv);
    }
}

extern "C" void kernel_launch(void* const* d_in, const int* in_sizes, int n_in,
                              void* d_out, int out_size, void* d_ws, size_t ws_size,
                              hipStream_t stream) {
    const float* x     = (const float*)d_in[0];
    const int*   batch = (const int*)d_in[1];
    float*       out   = (float*)d_out;
    const int N = in_sizes[1];              // number of nodes (1,000,000)
    const int G = out_size / 256;           // number of graphs (1024)

    meanpool_kernel<<<G, 256, 0, stream>>>(x, batch, out, N);
}